// Round 10
// baseline (277.096 us; speedup 1.0000x reference)
//
#include <hip/hip_runtime.h>

#define Bn 16384
#define Hn 128
#define Gn 5
#define Tn 12

typedef __attribute__((ext_vector_type(8))) __bf16 bf16x8;
typedef __attribute__((ext_vector_type(4))) float f32x4;
typedef __attribute__((ext_vector_type(4))) unsigned int u32x4;
typedef __attribute__((ext_vector_type(2))) unsigned int u32x2;
typedef unsigned int u32;
typedef unsigned short u16;

#define MFMA(a, b, c) __builtin_amdgcn_mfma_f32_16x16x32_bf16((a), (b), (c), 0, 0, 0)

__device__ __forceinline__ u16 f2bf(float f) { return __builtin_bit_cast(u16, (__bf16)f); }
__device__ __forceinline__ u32 pk2(float a, float b) { return (u32)f2bf(a) | ((u32)f2bf(b) << 16); }

// Swizzled byte offsets (chunk-XOR): [rows][128] bf16 tile, 256 B rows, 16 chunks of 16 B
__device__ __forceinline__ int hbsw(int row, int bytein) {
    return row * 256 + ((((bytein >> 4) ^ row) & 15) << 4) + (bytein & 15);
}
// [rows][64] bf16 tile: 128 B rows, 8 chunks
__device__ __forceinline__ int pbsw(int row, int bytein) {
    return row * 128 + ((((bytein >> 4) ^ row) & 7) << 4) + (bytein & 15);
}

// ---------------- Kernel 1: goals + goal_probs (phase A) ----------------
__global__ __launch_bounds__(256) void k_phaseA(
    const float* __restrict__ eh, const float* __restrict__ lastpos,
    const float* __restrict__ gp_w1, const float* __restrict__ gp_b1,
    const float* __restrict__ gp_w2, const float* __restrict__ gp_b2,
    const float* __restrict__ pr_w1, const float* __restrict__ pr_b1,
    const float* __restrict__ pr_w2, const float* __restrict__ pr_b2,
    float* __restrict__ goals_o, float* __restrict__ probs_o)
{
    __shared__ __align__(16) char eT[64 * 256];  // [64][128] bf16
    __shared__ __align__(16) char gT[64 * 256];  // [64][128] bf16
    __shared__ __align__(16) char pT[64 * 128];  // [64][64] bf16
    __shared__ float lgT[64 * 8];

    const int tid = threadIdx.x;
    const int lane = tid & 63;
    const int wv = tid >> 6;           // 0..3
    const int lg = lane >> 4, li = lane & 15;
    const int r0 = blockIdx.x * 64;
    const int rowbase = wv * 16;

    // stage eh -> bf16 LDS (swizzled)
    {
        int row = tid >> 2, seg = tid & 3;
        const float* src = eh + (size_t)(r0 + row) * Hn + seg * 32;
#pragma unroll
        for (int cc = 0; cc < 4; ++cc) {
            u32 p0 = pk2(src[cc * 8 + 0], src[cc * 8 + 1]);
            u32 p1 = pk2(src[cc * 8 + 2], src[cc * 8 + 3]);
            u32 p2 = pk2(src[cc * 8 + 4], src[cc * 8 + 5]);
            u32 p3 = pk2(src[cc * 8 + 6], src[cc * 8 + 7]);
            *(u32x4*)(eT + hbsw(row, seg * 64 + cc * 16)) = (u32x4){p0, p1, p2, p3};
        }
    }
    __syncthreads();

    bf16x8 Ae[4];
#pragma unroll
    for (int kc = 0; kc < 4; ++kc)
        Ae[kc] = *(const bf16x8*)(eT + hbsw(rowbase + li, kc * 64 + lg * 16));

    // g_hid = relu(eh @ gp_w1 + gp_b1)
#pragma unroll 1
    for (int nt = 0; nt < 8; ++nt) {
        int c1 = nt * 16 + li;
        f32x4 acc = {0.f, 0.f, 0.f, 0.f};
#pragma unroll
        for (int kc = 0; kc < 4; ++kc) {
            bf16x8 bfr;
#pragma unroll
            for (int j = 0; j < 8; ++j)
                bfr[j] = (__bf16)gp_w1[(size_t)(kc * 32 + lg * 8 + j) * Hn + c1];
            acc = MFMA(Ae[kc], bfr, acc);
        }
        float bias = gp_b1[c1];
#pragma unroll
        for (int r = 0; r < 4; ++r) {
            int row = rowbase + lg * 4 + r;
            float v = fmaxf(acc[r] + bias, 0.f);
            *(u16*)(gT + hbsw(row, c1 * 2)) = f2bf(v);
        }
    }
    __syncthreads();

    // goals = g_hid @ gp_w2 + gp_b2 + last_pos
    {
        bf16x8 Ag[4];
#pragma unroll
        for (int kc = 0; kc < 4; ++kc)
            Ag[kc] = *(const bf16x8*)(gT + hbsw(rowbase + li, kc * 64 + lg * 16));
        f32x4 acc = {0.f, 0.f, 0.f, 0.f};
#pragma unroll
        for (int kc = 0; kc < 4; ++kc) {
            bf16x8 bfr;
#pragma unroll
            for (int j = 0; j < 8; ++j) {
                int k = kc * 32 + lg * 8 + j;
                bfr[j] = (li < 10) ? (__bf16)gp_w2[k * 10 + li] : (__bf16)0.f;
            }
            acc = MFMA(Ag[kc], bfr, acc);
        }
        if (li < 10) {
            float b2 = gp_b2[li];
#pragma unroll
            for (int r = 0; r < 4; ++r) {
                int b = r0 + rowbase + lg * 4 + r;
                float v = acc[r] + b2 + lastpos[(size_t)b * 2 + (li & 1)];
                goals_o[(size_t)b * 10 + li] = v;
            }
        }
    }

    // p_hid = relu(eh @ pr_w1 + pr_b1)
#pragma unroll 1
    for (int nt = 0; nt < 4; ++nt) {
        int c1 = nt * 16 + li;
        f32x4 acc = {0.f, 0.f, 0.f, 0.f};
#pragma unroll
        for (int kc = 0; kc < 4; ++kc) {
            bf16x8 bfr;
#pragma unroll
            for (int j = 0; j < 8; ++j)
                bfr[j] = (__bf16)pr_w1[(size_t)(kc * 32 + lg * 8 + j) * 64 + c1];
            acc = MFMA(Ae[kc], bfr, acc);
        }
        float bias = pr_b1[c1];
#pragma unroll
        for (int r = 0; r < 4; ++r) {
            int row = rowbase + lg * 4 + r;
            float v = fmaxf(acc[r] + bias, 0.f);
            *(u16*)(pT + pbsw(row, c1 * 2)) = f2bf(v);
        }
    }
    __syncthreads();

    // logits = p_hid @ pr_w2 + pr_b2
    {
        bf16x8 Ap[2];
#pragma unroll
        for (int kc = 0; kc < 2; ++kc)
            Ap[kc] = *(const bf16x8*)(pT + pbsw(rowbase + li, kc * 64 + lg * 16));
        f32x4 acc = {0.f, 0.f, 0.f, 0.f};
#pragma unroll
        for (int kc = 0; kc < 2; ++kc) {
            bf16x8 bfr;
#pragma unroll
            for (int j = 0; j < 8; ++j) {
                int k = kc * 32 + lg * 8 + j;
                bfr[j] = (li < 5) ? (__bf16)pr_w2[k * 5 + li] : (__bf16)0.f;
            }
            acc = MFMA(Ap[kc], bfr, acc);
        }
        if (li < 5) {
            float b2 = pr_b2[li];
#pragma unroll
            for (int r = 0; r < 4; ++r) {
                int row = rowbase + lg * 4 + r;
                lgT[row * 8 + li] = acc[r] + b2;
            }
        }
    }
    __syncthreads();

    if (tid < 64) {
        int row = tid;
        float v0 = lgT[row * 8 + 0], v1 = lgT[row * 8 + 1], v2 = lgT[row * 8 + 2];
        float v3 = lgT[row * 8 + 3], v4 = lgT[row * 8 + 4];
        float mx = fmaxf(fmaxf(fmaxf(v0, v1), fmaxf(v2, v3)), v4);
        float e0 = __builtin_amdgcn_exp2f((v0 - mx) * 1.44269504f);
        float e1 = __builtin_amdgcn_exp2f((v1 - mx) * 1.44269504f);
        float e2 = __builtin_amdgcn_exp2f((v2 - mx) * 1.44269504f);
        float e3 = __builtin_amdgcn_exp2f((v3 - mx) * 1.44269504f);
        float e4 = __builtin_amdgcn_exp2f((v4 - mx) * 1.44269504f);
        float rs = __builtin_amdgcn_rcpf(e0 + e1 + e2 + e3 + e4);
        size_t ob = (size_t)(r0 + row) * 5;
        probs_o[ob + 0] = e0 * rs;
        probs_o[ob + 1] = e1 * rs;
        probs_o[ob + 2] = e2 * rs;
        probs_o[ob + 3] = e3 * rs;
        probs_o[ob + 4] = e4 * rs;
    }
}

// ---------------- Kernel 2: LSTM rollout ----------------
// R8 structure (double-buffered h tile, ONE barrier per step, pos/goals in
// LDS, folded activations, setprio) at MT=8 so BOTH resource constraints hold:
//  (1) no spill: c[8] saves 8 regs vs R8's 120 -> ~112 arch VGPRs  [R9 lesson:
//      any spill also caps occupancy via scratch]
//  (2) LDS = 2x32KB + pos/goals ~ 68KB < 80KB -> TWO blocks per CU
// Two de-phased blocks per CU overlap VALU/trans of one with MFMA of the
// other and absorb barrier drains. Grid 640 = 512 co-resident + 128 tail.
// Register-cap law (R2/R5/R6/R9): 512-thread kernels pinned at <=128 arch
// VGPRs; demand must fit or scratch traffic + occupancy loss follows.
__global__ __launch_bounds__(512) void k_lstm(
    const float* __restrict__ eh, const float* __restrict__ ec,
    const float* __restrict__ lastpos,
    const float* __restrict__ w_ih, const float* __restrict__ w_hh,
    const float* __restrict__ b_ih, const float* __restrict__ b_hh,
    const float* __restrict__ ph_w, const float* __restrict__ ph_b,
    const float* __restrict__ goals_o, float* __restrict__ preds)
{
#define MT 8                        // m-tiles per block
#define ROWS (MT * 16)              // 128
#define BUFB (ROWS * 256)           // 32768 B per buffer
    __shared__ __align__(16) char hT[2][BUFB];  // double-buffered [128][128] bf16, swizzled
    __shared__ float2 posb[2][ROWS];            // double-buffered positions
    __shared__ u32 gpkT[ROWS];                  // goals packed bf16x2

    const int tid = threadIdx.x;
    const int lane = tid & 63;
    const int wv = tid >> 6;            // 0..7
    const int lg = lane >> 4, li = lane & 15;
    const int r0 = blockIdx.x * ROWS;

    const float NL = -1.44269504f;      // -log2e (i,f,o)
    const float PG = 2.88539008f;       // +2*log2e (g, tanh(c) argument)

    // --- weight fragments in registers (scale-folded)
    bf16x8 Wh[4][4];   // w_hh, [gate][kc]
    bf16x8 Wx[4];      // [w_ih rows 0..3; b_ih+b_hh at k=4; 0...], K=32
#pragma unroll
    for (int gt = 0; gt < 4; ++gt) {
        const float s = (gt == 2) ? PG : NL;
        const int cg = gt * 128 + wv * 16 + li;
#pragma unroll
        for (int kc = 0; kc < 4; ++kc) {
            bf16x8 f;
#pragma unroll
            for (int j = 0; j < 8; ++j)
                f[j] = (__bf16)(w_hh[(size_t)(kc * 32 + lg * 8 + j) * 512 + cg] * s);
            Wh[gt][kc] = f;
        }
        bf16x8 fx;
#pragma unroll
        for (int j = 0; j < 8; ++j) {
            int k = lg * 8 + j;
            float v = 0.f;
            if (k < 4) v = w_ih[k * 512 + cg] * s;
            else if (k == 4) v = (b_ih[cg] + b_hh[cg]) * s;
            fx[j] = (__bf16)v;
        }
        Wx[gt] = fx;
    }

    // --- ph_w A-fragments: A row 0 = ph_w[:,0] (li==0 lanes), others ph_w[:,1]
    bf16x8 php[4];
#pragma unroll
    for (int kc = 0; kc < 4; ++kc) {
        u32 w[4];
#pragma unroll
        for (int jp = 0; jp < 4; ++jp) {
            int k = kc * 32 + lg * 8 + jp * 2;
            u32 xw = pk2(ph_w[k * 2 + 0], ph_w[k * 2 + 2]);
            u32 yw = pk2(ph_w[k * 2 + 1], ph_w[k * 2 + 3]);
            w[jp] = (li == 0) ? xw : yw;
        }
        php[kc] = __builtin_bit_cast(bf16x8, (u32x4){w[0], w[1], w[2], w[3]});
    }
    const float phb0 = ph_b[0], phb1 = ph_b[1];

    // --- hoisted swizzled LDS offsets
    const int ro0 = hbsw(li, 0 + lg * 16);
    const int ro1 = hbsw(li, 64 + lg * 16);
    const int ro2 = hbsw(li, 128 + lg * 16);
    const int ro3 = hbsw(li, 192 + lg * 16);
    const int wo  = hbsw(li, wv * 32 + lg * 8);

    // --- stage h0 = encoder_hidden (broadcast over g) into buffer 0
#pragma unroll
    for (int it = 0; it < 4; ++it) {
        int chunk = tid + it * 512;          // 2048 chunks of 16 B
        int row = chunk >> 4, seg = chunk & 15;
        const float* src = eh + (size_t)((r0 + row) / 5) * Hn + seg * 8;
        u32 p0 = pk2(src[0], src[1]);
        u32 p1 = pk2(src[2], src[3]);
        u32 p2 = pk2(src[4], src[5]);
        u32 p3 = pk2(src[6], src[7]);
        *(u32x4*)(hT[0] + hbsw(row, seg * 16)) = (u32x4){p0, p1, p2, p3};
    }
    // --- stage pos (both buffers) + packed goals
    if (tid < ROWS) {
        int gr = r0 + tid;
        float2 p = *(const float2*)(lastpos + (size_t)(gr / 5) * 2);
        posb[0][tid] = p;
        posb[1][tid] = p;
        float2 g2 = *(const float2*)(goals_o + (size_t)gr * 2);
        gpkT[tid] = pk2(g2.x, g2.y);
    }

    // --- c0 registers (f32 master): c[m][r] at (batch m*16+li, hidden col wv*16+lg*4+r)
    f32x4 c[MT];
#pragma unroll
    for (int m = 0; m < MT; ++m) {
        int b = (r0 + m * 16 + li) / 5;
        float4 cv = *(const float4*)(ec + (size_t)b * Hn + wv * 16 + lg * 4);
        c[m] = (f32x4){cv.x, cv.y, cv.z, cv.w};
    }

    __syncthreads();

#pragma unroll 1
    for (int t = 0; t < Tn; ++t) {
        const char* rbp = hT[0] + (t & 1) * BUFB;
        char* wbp = hT[0] + ((t & 1) ^ 1) * BUFB;
        const float2* posR = posb[t & 1];
        float2* posW = posb[(t & 1) ^ 1];
#pragma unroll
        for (int m = 0; m < MT; ++m) {
            const int mo = m * 4096;
            bf16x8 H0 = *(const bf16x8*)(rbp + ro0 + mo);
            bf16x8 H1 = *(const bf16x8*)(rbp + ro1 + mo);
            bf16x8 H2 = *(const bf16x8*)(rbp + ro2 + mo);
            bf16x8 H3 = *(const bf16x8*)(rbp + ro3 + mo);

            f32x4 a0 = {0.f, 0.f, 0.f, 0.f}, a1 = {0.f, 0.f, 0.f, 0.f};
            f32x4 a2 = {0.f, 0.f, 0.f, 0.f}, a3 = {0.f, 0.f, 0.f, 0.f};
            __builtin_amdgcn_s_setprio(1);
            a0 = MFMA(Wh[0][0], H0, a0); a1 = MFMA(Wh[1][0], H0, a1);
            a2 = MFMA(Wh[2][0], H0, a2); a3 = MFMA(Wh[3][0], H0, a3);
            a0 = MFMA(Wh[0][1], H1, a0); a1 = MFMA(Wh[1][1], H1, a1);
            a2 = MFMA(Wh[2][1], H1, a2); a3 = MFMA(Wh[3][1], H1, a3);
            a0 = MFMA(Wh[0][2], H2, a0); a1 = MFMA(Wh[1][2], H2, a1);
            a2 = MFMA(Wh[2][2], H2, a2); a3 = MFMA(Wh[3][2], H2, a3);
            a0 = MFMA(Wh[0][3], H3, a0); a1 = MFMA(Wh[1][3], H3, a1);
            a2 = MFMA(Wh[2][3], H3, a2); a3 = MFMA(Wh[3][3], H3, a3);
            __builtin_amdgcn_s_setprio(0);

            float2 pp = posR[m * 16 + li];
            float pxv = pp.x, pyv = pp.y;
            if (t > 0) {
                // pos_t = pos_{t-1} + h_t @ ph_w   (valid in lg==0 lanes)
                f32x4 pacc = {0.f, 0.f, 0.f, 0.f};
                __builtin_amdgcn_s_setprio(1);
                pacc = MFMA(php[0], H0, pacc);
                pacc = MFMA(php[1], H1, pacc);
                pacc = MFMA(php[2], H2, pacc);
                pacc = MFMA(php[3], H3, pacc);
                __builtin_amdgcn_s_setprio(0);
                pxv += pacc[0] + phb0;
                pyv += pacc[1] + phb1;
                if ((m == wv || (m + 8) == wv + 8) && (m & 7) == wv && lg == 0) {
                    posW[m * 16 + li] = make_float2(pxv, pyv);
                    size_t o = ((size_t)(r0 + m * 16 + li) * Tn + (t - 1)) * 2;
                    *(float2*)(preds + o) = make_float2(pxv, pyv);
                }
            }

            // x-fragment rows k=0..4 = [px,py,gx,gy,1]; lg>0 rows hit zero Wx rows
            u32 gk = gpkT[m * 16 + li];
            bf16x8 xf = __builtin_bit_cast(bf16x8,
                (u32x4){pk2(pxv, pyv), gk, 0x00003F80u, 0u});
            __builtin_amdgcn_s_setprio(1);
            a0 = MFMA(Wx[0], xf, a0);
            a1 = MFMA(Wx[1], xf, a1);
            a2 = MFMA(Wx[2], xf, a2);
            a3 = MFMA(Wx[3], xf, a3);
            __builtin_amdgcn_s_setprio(0);

            u32 w0, w1;
            {
                // folded activations (exact reassociation of sigmoid/tanh):
                // A=e^-i, F=e^-f, B=e^2g, D=e^-o (prescaled weights), then
                // cn = [c*P+(B-1)(1+F)]*rcp(P*(1+F)), P=(1+A)(1+B)
                // hv = (C-1)*rcp((1+D)(C+1)), C=e^{2*cn}
                float hvv[4];
#pragma unroll
                for (int r = 0; r < 4; ++r) {
                    float A = __builtin_amdgcn_exp2f(a0[r]);
                    float F = __builtin_amdgcn_exp2f(a1[r]);
                    float B = __builtin_amdgcn_exp2f(a2[r]);
                    float D = __builtin_amdgcn_exp2f(a3[r]);
                    float P = (1.0f + A) * (1.0f + B);
                    float Fp = 1.0f + F;
                    float R = __builtin_amdgcn_rcpf(P * Fp);
                    float cn = (c[m][r] * P + (B - 1.0f) * Fp) * R;
                    c[m][r] = cn;
                    float C = __builtin_amdgcn_exp2f(PG * cn);
                    float R2 = __builtin_amdgcn_rcpf((1.0f + D) * (C + 1.0f));
                    hvv[r] = (C - 1.0f) * R2;
                }
                w0 = pk2(hvv[0], hvv[1]);
                w1 = pk2(hvv[2], hvv[3]);
            }
            *(u32x2*)(wbp + wo + mo) = (u32x2){w0, w1};
        }
        __syncthreads();   // h_new + pos visible; old-buffer reads all done pre-barrier
    }

    // --- epilogue: preds[T-1] = pos_T from h_T (buffer 0, Tn even); one tile per wave
#pragma unroll
    for (int m = 0; m < MT; ++m) {
        if (m != wv) continue;
        const char* rbp = hT[0];
        const int mo = m * 4096;
        bf16x8 H0 = *(const bf16x8*)(rbp + ro0 + mo);
        bf16x8 H1 = *(const bf16x8*)(rbp + ro1 + mo);
        bf16x8 H2 = *(const bf16x8*)(rbp + ro2 + mo);
        bf16x8 H3 = *(const bf16x8*)(rbp + ro3 + mo);
        f32x4 pacc = {0.f, 0.f, 0.f, 0.f};
        pacc = MFMA(php[0], H0, pacc);
        pacc = MFMA(php[1], H1, pacc);
        pacc = MFMA(php[2], H2, pacc);
        pacc = MFMA(php[3], H3, pacc);
        if (lg == 0) {
            float2 pp = posb[Tn & 1][m * 16 + li];
            float fx = pp.x + pacc[0] + phb0;
            float fy = pp.y + pacc[1] + phb1;
            size_t o = ((size_t)(r0 + m * 16 + li) * Tn + (Tn - 1)) * 2;
            *(float2*)(preds + o) = make_float2(fx, fy);
        }
    }
#undef MT
#undef ROWS
#undef BUFB
}

extern "C" void kernel_launch(void* const* d_in, const int* in_sizes, int n_in,
                              void* d_out, int out_size, void* d_ws, size_t ws_size,
                              hipStream_t stream)
{
    (void)in_sizes; (void)n_in; (void)out_size; (void)d_ws; (void)ws_size;
    const float* eh   = (const float*)d_in[0];
    const float* ec   = (const float*)d_in[1];
    const float* lp   = (const float*)d_in[2];
    const float* gpw1 = (const float*)d_in[3];
    const float* gpb1 = (const float*)d_in[4];
    const float* gpw2 = (const float*)d_in[5];
    const float* gpb2 = (const float*)d_in[6];
    const float* prw1 = (const float*)d_in[7];
    const float* prb1 = (const float*)d_in[8];
    const float* prw2 = (const float*)d_in[9];
    const float* prb2 = (const float*)d_in[10];
    const float* wih  = (const float*)d_in[11];
    const float* whh  = (const float*)d_in[12];
    const float* bih  = (const float*)d_in[13];
    const float* bhh  = (const float*)d_in[14];
    const float* phw  = (const float*)d_in[15];
    const float* phb  = (const float*)d_in[16];

    float* out = (float*)d_out;
    float* preds = out;                                            // [B,G,T,2]
    float* goals = out + (size_t)Bn * Gn * Tn * 2;                 // [B,G,2]
    float* probs = out + (size_t)Bn * Gn * Tn * 2 + (size_t)Bn * Gn * 2;  // [B,G]

    k_phaseA<<<Bn / 64, 256, 0, stream>>>(eh, lp, gpw1, gpb1, gpw2, gpb2,
                                          prw1, prb1, prw2, prb2, goals, probs);
    k_lstm<<<(Bn * Gn) / 128, 512, 0, stream>>>(eh, ec, lp, wih, whh, bih, bhh,
                                                phw, phb, goals, preds);
}

// Round 11
// 225.915 us; speedup vs baseline: 1.2266x; 1.2266x over previous
//
#include <hip/hip_runtime.h>

#define Bn 16384
#define Hn 128
#define Gn 5
#define Tn 12

typedef __attribute__((ext_vector_type(8))) __bf16 bf16x8;
typedef __attribute__((ext_vector_type(4))) float f32x4;
typedef __attribute__((ext_vector_type(4))) unsigned int u32x4;
typedef __attribute__((ext_vector_type(2))) unsigned int u32x2;
typedef unsigned int u32;
typedef unsigned short u16;

#define MFMA(a, b, c) __builtin_amdgcn_mfma_f32_16x16x32_bf16((a), (b), (c), 0, 0, 0)

__device__ __forceinline__ u16 f2bf(float f) { return __builtin_bit_cast(u16, (__bf16)f); }
__device__ __forceinline__ u32 pk2(float a, float b) { return (u32)f2bf(a) | ((u32)f2bf(b) << 16); }

// Swizzled byte offsets (chunk-XOR): [rows][128] bf16 tile, 256 B rows, 16 chunks of 16 B
__device__ __forceinline__ int hbsw(int row, int bytein) {
    return row * 256 + ((((bytein >> 4) ^ row) & 15) << 4) + (bytein & 15);
}
// [rows][64] bf16 tile: 128 B rows, 8 chunks
__device__ __forceinline__ int pbsw(int row, int bytein) {
    return row * 128 + ((((bytein >> 4) ^ row) & 7) << 4) + (bytein & 15);
}

// ---------------- Kernel 1: goals + goal_probs (phase A) ----------------
__global__ __launch_bounds__(256) void k_phaseA(
    const float* __restrict__ eh, const float* __restrict__ lastpos,
    const float* __restrict__ gp_w1, const float* __restrict__ gp_b1,
    const float* __restrict__ gp_w2, const float* __restrict__ gp_b2,
    const float* __restrict__ pr_w1, const float* __restrict__ pr_b1,
    const float* __restrict__ pr_w2, const float* __restrict__ pr_b2,
    float* __restrict__ goals_o, float* __restrict__ probs_o)
{
    __shared__ __align__(16) char eT[64 * 256];  // [64][128] bf16
    __shared__ __align__(16) char gT[64 * 256];  // [64][128] bf16
    __shared__ __align__(16) char pT[64 * 128];  // [64][64] bf16
    __shared__ float lgT[64 * 8];

    const int tid = threadIdx.x;
    const int lane = tid & 63;
    const int wv = tid >> 6;           // 0..3
    const int lg = lane >> 4, li = lane & 15;
    const int r0 = blockIdx.x * 64;
    const int rowbase = wv * 16;

    // stage eh -> bf16 LDS (swizzled)
    {
        int row = tid >> 2, seg = tid & 3;
        const float* src = eh + (size_t)(r0 + row) * Hn + seg * 32;
#pragma unroll
        for (int cc = 0; cc < 4; ++cc) {
            u32 p0 = pk2(src[cc * 8 + 0], src[cc * 8 + 1]);
            u32 p1 = pk2(src[cc * 8 + 2], src[cc * 8 + 3]);
            u32 p2 = pk2(src[cc * 8 + 4], src[cc * 8 + 5]);
            u32 p3 = pk2(src[cc * 8 + 6], src[cc * 8 + 7]);
            *(u32x4*)(eT + hbsw(row, seg * 64 + cc * 16)) = (u32x4){p0, p1, p2, p3};
        }
    }
    __syncthreads();

    bf16x8 Ae[4];
#pragma unroll
    for (int kc = 0; kc < 4; ++kc)
        Ae[kc] = *(const bf16x8*)(eT + hbsw(rowbase + li, kc * 64 + lg * 16));

    // g_hid = relu(eh @ gp_w1 + gp_b1)
#pragma unroll 1
    for (int nt = 0; nt < 8; ++nt) {
        int c1 = nt * 16 + li;
        f32x4 acc = {0.f, 0.f, 0.f, 0.f};
#pragma unroll
        for (int kc = 0; kc < 4; ++kc) {
            bf16x8 bfr;
#pragma unroll
            for (int j = 0; j < 8; ++j)
                bfr[j] = (__bf16)gp_w1[(size_t)(kc * 32 + lg * 8 + j) * Hn + c1];
            acc = MFMA(Ae[kc], bfr, acc);
        }
        float bias = gp_b1[c1];
#pragma unroll
        for (int r = 0; r < 4; ++r) {
            int row = rowbase + lg * 4 + r;
            float v = fmaxf(acc[r] + bias, 0.f);
            *(u16*)(gT + hbsw(row, c1 * 2)) = f2bf(v);
        }
    }
    __syncthreads();

    // goals = g_hid @ gp_w2 + gp_b2 + last_pos
    {
        bf16x8 Ag[4];
#pragma unroll
        for (int kc = 0; kc < 4; ++kc)
            Ag[kc] = *(const bf16x8*)(gT + hbsw(rowbase + li, kc * 64 + lg * 16));
        f32x4 acc = {0.f, 0.f, 0.f, 0.f};
#pragma unroll
        for (int kc = 0; kc < 4; ++kc) {
            bf16x8 bfr;
#pragma unroll
            for (int j = 0; j < 8; ++j) {
                int k = kc * 32 + lg * 8 + j;
                bfr[j] = (li < 10) ? (__bf16)gp_w2[k * 10 + li] : (__bf16)0.f;
            }
            acc = MFMA(Ag[kc], bfr, acc);
        }
        if (li < 10) {
            float b2 = gp_b2[li];
#pragma unroll
            for (int r = 0; r < 4; ++r) {
                int b = r0 + rowbase + lg * 4 + r;
                float v = acc[r] + b2 + lastpos[(size_t)b * 2 + (li & 1)];
                goals_o[(size_t)b * 10 + li] = v;
            }
        }
    }

    // p_hid = relu(eh @ pr_w1 + pr_b1)
#pragma unroll 1
    for (int nt = 0; nt < 4; ++nt) {
        int c1 = nt * 16 + li;
        f32x4 acc = {0.f, 0.f, 0.f, 0.f};
#pragma unroll
        for (int kc = 0; kc < 4; ++kc) {
            bf16x8 bfr;
#pragma unroll
            for (int j = 0; j < 8; ++j)
                bfr[j] = (__bf16)pr_w1[(size_t)(kc * 32 + lg * 8 + j) * 64 + c1];
            acc = MFMA(Ae[kc], bfr, acc);
        }
        float bias = pr_b1[c1];
#pragma unroll
        for (int r = 0; r < 4; ++r) {
            int row = rowbase + lg * 4 + r;
            float v = fmaxf(acc[r] + bias, 0.f);
            *(u16*)(pT + pbsw(row, c1 * 2)) = f2bf(v);
        }
    }
    __syncthreads();

    // logits = p_hid @ pr_w2 + pr_b2
    {
        bf16x8 Ap[2];
#pragma unroll
        for (int kc = 0; kc < 2; ++kc)
            Ap[kc] = *(const bf16x8*)(pT + pbsw(rowbase + li, kc * 64 + lg * 16));
        f32x4 acc = {0.f, 0.f, 0.f, 0.f};
#pragma unroll
        for (int kc = 0; kc < 2; ++kc) {
            bf16x8 bfr;
#pragma unroll
            for (int j = 0; j < 8; ++j) {
                int k = kc * 32 + lg * 8 + j;
                bfr[j] = (li < 5) ? (__bf16)pr_w2[k * 5 + li] : (__bf16)0.f;
            }
            acc = MFMA(Ap[kc], bfr, acc);
        }
        if (li < 5) {
            float b2 = pr_b2[li];
#pragma unroll
            for (int r = 0; r < 4; ++r) {
                int row = rowbase + lg * 4 + r;
                lgT[row * 8 + li] = acc[r] + b2;
            }
        }
    }
    __syncthreads();

    if (tid < 64) {
        int row = tid;
        float v0 = lgT[row * 8 + 0], v1 = lgT[row * 8 + 1], v2 = lgT[row * 8 + 2];
        float v3 = lgT[row * 8 + 3], v4 = lgT[row * 8 + 4];
        float mx = fmaxf(fmaxf(fmaxf(v0, v1), fmaxf(v2, v3)), v4);
        float e0 = __builtin_amdgcn_exp2f((v0 - mx) * 1.44269504f);
        float e1 = __builtin_amdgcn_exp2f((v1 - mx) * 1.44269504f);
        float e2 = __builtin_amdgcn_exp2f((v2 - mx) * 1.44269504f);
        float e3 = __builtin_amdgcn_exp2f((v3 - mx) * 1.44269504f);
        float e4 = __builtin_amdgcn_exp2f((v4 - mx) * 1.44269504f);
        float rs = __builtin_amdgcn_rcpf(e0 + e1 + e2 + e3 + e4);
        size_t ob = (size_t)(r0 + row) * 5;
        probs_o[ob + 0] = e0 * rs;
        probs_o[ob + 1] = e1 * rs;
        probs_o[ob + 2] = e2 * rs;
        probs_o[ob + 3] = e3 * rs;
        probs_o[ob + 4] = e4 * rs;
    }
}

// ---------------- Kernel 2: LSTM rollout ----------------
// R8 config (MT=10, 160 rows/block, 512 blocks = exactly 2 rounds/CU, double-
// buffered h tile, ONE barrier/step, pos/goals in LDS, folded activations).
// NEW (R11): explicit two-stage software pipeline over m-tiles (T15 pattern).
// Two named accumulator sets A/B; tile m+1's {ds_read + gate/pacc/Wx MFMAs}
// issue BEFORE tile m's activation/pack/ds_write runs -> breaks the
// single-accumulator-set serialization between tiles. All tile indices are
// literals (static indexing; runtime-indexed regs would go to scratch).
// Occupancy is structurally 8 waves/CU (unified VGPR+AGPR > 128/wave; R10
// proved LDS is not the limiter), so the lever is per-wave ILP.
__global__ __launch_bounds__(512) void k_lstm(
    const float* __restrict__ eh, const float* __restrict__ ec,
    const float* __restrict__ lastpos,
    const float* __restrict__ w_ih, const float* __restrict__ w_hh,
    const float* __restrict__ b_ih, const float* __restrict__ b_hh,
    const float* __restrict__ ph_w, const float* __restrict__ ph_b,
    const float* __restrict__ goals_o, float* __restrict__ preds)
{
#define MT 10                       // m-tiles per block
#define ROWS (MT * 16)              // 160
#define BUFB (ROWS * 256)           // 40960 B per buffer
    __shared__ __align__(16) char hT[2][BUFB];  // double-buffered [160][128] bf16, swizzled
    __shared__ float2 posb[2][ROWS];            // double-buffered positions
    __shared__ u32 gpkT[ROWS];                  // goals packed bf16x2

    const int tid = threadIdx.x;
    const int lane = tid & 63;
    const int wv = tid >> 6;            // 0..7
    const int lg = lane >> 4, li = lane & 15;
    const int r0 = blockIdx.x * ROWS;

    const float NL = -1.44269504f;      // -log2e (i,f,o)
    const float PG = 2.88539008f;       // +2*log2e (g, tanh(c) argument)

    // --- weight fragments in registers (scale-folded)
    bf16x8 Wh[4][4];   // w_hh, [gate][kc]
    bf16x8 Wx[4];      // [w_ih rows 0..3; b_ih+b_hh at k=4; 0...], K=32
#pragma unroll
    for (int gt = 0; gt < 4; ++gt) {
        const float s = (gt == 2) ? PG : NL;
        const int cg = gt * 128 + wv * 16 + li;
#pragma unroll
        for (int kc = 0; kc < 4; ++kc) {
            bf16x8 f;
#pragma unroll
            for (int j = 0; j < 8; ++j)
                f[j] = (__bf16)(w_hh[(size_t)(kc * 32 + lg * 8 + j) * 512 + cg] * s);
            Wh[gt][kc] = f;
        }
        bf16x8 fx;
#pragma unroll
        for (int j = 0; j < 8; ++j) {
            int k = lg * 8 + j;
            float v = 0.f;
            if (k < 4) v = w_ih[k * 512 + cg] * s;
            else if (k == 4) v = (b_ih[cg] + b_hh[cg]) * s;
            fx[j] = (__bf16)v;
        }
        Wx[gt] = fx;
    }

    // --- ph_w A-fragments: A row 0 = ph_w[:,0] (li==0 lanes), others ph_w[:,1]
    bf16x8 php[4];
#pragma unroll
    for (int kc = 0; kc < 4; ++kc) {
        u32 w[4];
#pragma unroll
        for (int jp = 0; jp < 4; ++jp) {
            int k = kc * 32 + lg * 8 + jp * 2;
            u32 xw = pk2(ph_w[k * 2 + 0], ph_w[k * 2 + 2]);
            u32 yw = pk2(ph_w[k * 2 + 1], ph_w[k * 2 + 3]);
            w[jp] = (li == 0) ? xw : yw;
        }
        php[kc] = __builtin_bit_cast(bf16x8, (u32x4){w[0], w[1], w[2], w[3]});
    }
    const float phb0 = ph_b[0], phb1 = ph_b[1];

    // --- hoisted swizzled LDS offsets
    const int ro0 = hbsw(li, 0 + lg * 16);
    const int ro1 = hbsw(li, 64 + lg * 16);
    const int ro2 = hbsw(li, 128 + lg * 16);
    const int ro3 = hbsw(li, 192 + lg * 16);
    const int wo  = hbsw(li, wv * 32 + lg * 8);

    // --- stage h0 = encoder_hidden (broadcast over g) into buffer 0
#pragma unroll
    for (int it = 0; it < 5; ++it) {
        int chunk = tid + it * 512;          // 2560 chunks of 16 B
        int row = chunk >> 4, seg = chunk & 15;
        const float* src = eh + (size_t)((r0 + row) / 5) * Hn + seg * 8;
        u32 p0 = pk2(src[0], src[1]);
        u32 p1 = pk2(src[2], src[3]);
        u32 p2 = pk2(src[4], src[5]);
        u32 p3 = pk2(src[6], src[7]);
        *(u32x4*)(hT[0] + hbsw(row, seg * 16)) = (u32x4){p0, p1, p2, p3};
    }
    // --- stage pos (both buffers) + packed goals
    if (tid < ROWS) {
        int gr = r0 + tid;
        float2 p = *(const float2*)(lastpos + (size_t)(gr / 5) * 2);
        posb[0][tid] = p;
        posb[1][tid] = p;
        float2 g2 = *(const float2*)(goals_o + (size_t)gr * 2);
        gpkT[tid] = pk2(g2.x, g2.y);
    }

    // --- c0 registers (f32 master): c[m][r] at (batch m*16+li, hidden col wv*16+lg*4+r)
    f32x4 c[MT];
#pragma unroll
    for (int m = 0; m < MT; ++m) {
        int b = (r0 + m * 16 + li) / 5;
        float4 cv = *(const float4*)(ec + (size_t)b * Hn + wv * 16 + lg * 4);
        c[m] = (f32x4){cv.x, cv.y, cv.z, cv.w};
    }

    __syncthreads();

#pragma unroll 1
    for (int t = 0; t < Tn; ++t) {
        const char* rbp = hT[0] + (t & 1) * BUFB;
        char* wbp = hT[0] + ((t & 1) ^ 1) * BUFB;
        const float2* posR = posb[t & 1];
        float2* posW = posb[(t & 1) ^ 1];

        f32x4 A0, A1, A2, A3;   // accumulator set A
        f32x4 B0, B1, B2, B3;   // accumulator set B

        // MFMA phase: ds_read H, 16 gate MFMAs, 4 pos MFMAs + pos update,
        // x-fragment, 4 Wx MFMAs. Leaves gates in (a0..a3).
        auto mfmaP = [&](int m, f32x4& a0, f32x4& a1, f32x4& a2, f32x4& a3) {
            const int mo = m * 4096;
            bf16x8 H0 = *(const bf16x8*)(rbp + ro0 + mo);
            bf16x8 H1 = *(const bf16x8*)(rbp + ro1 + mo);
            bf16x8 H2 = *(const bf16x8*)(rbp + ro2 + mo);
            bf16x8 H3 = *(const bf16x8*)(rbp + ro3 + mo);

            a0 = (f32x4){0.f, 0.f, 0.f, 0.f}; a1 = (f32x4){0.f, 0.f, 0.f, 0.f};
            a2 = (f32x4){0.f, 0.f, 0.f, 0.f}; a3 = (f32x4){0.f, 0.f, 0.f, 0.f};
            __builtin_amdgcn_s_setprio(1);
            a0 = MFMA(Wh[0][0], H0, a0); a1 = MFMA(Wh[1][0], H0, a1);
            a2 = MFMA(Wh[2][0], H0, a2); a3 = MFMA(Wh[3][0], H0, a3);
            a0 = MFMA(Wh[0][1], H1, a0); a1 = MFMA(Wh[1][1], H1, a1);
            a2 = MFMA(Wh[2][1], H1, a2); a3 = MFMA(Wh[3][1], H1, a3);
            a0 = MFMA(Wh[0][2], H2, a0); a1 = MFMA(Wh[1][2], H2, a1);
            a2 = MFMA(Wh[2][2], H2, a2); a3 = MFMA(Wh[3][2], H2, a3);
            a0 = MFMA(Wh[0][3], H3, a0); a1 = MFMA(Wh[1][3], H3, a1);
            a2 = MFMA(Wh[2][3], H3, a2); a3 = MFMA(Wh[3][3], H3, a3);
            __builtin_amdgcn_s_setprio(0);

            float2 pp = posR[m * 16 + li];
            float pxv = pp.x, pyv = pp.y;
            if (t > 0) {
                f32x4 pacc = {0.f, 0.f, 0.f, 0.f};
                __builtin_amdgcn_s_setprio(1);
                pacc = MFMA(php[0], H0, pacc);
                pacc = MFMA(php[1], H1, pacc);
                pacc = MFMA(php[2], H2, pacc);
                pacc = MFMA(php[3], H3, pacc);
                __builtin_amdgcn_s_setprio(0);
                pxv += pacc[0] + phb0;
                pyv += pacc[1] + phb1;
                if (((m & 7) == wv) && lg == 0) {
                    posW[m * 16 + li] = make_float2(pxv, pyv);
                    size_t o = ((size_t)(r0 + m * 16 + li) * Tn + (t - 1)) * 2;
                    *(float2*)(preds + o) = make_float2(pxv, pyv);
                }
            }

            u32 gk = gpkT[m * 16 + li];
            bf16x8 xf = __builtin_bit_cast(bf16x8,
                (u32x4){pk2(pxv, pyv), gk, 0x00003F80u, 0u});
            __builtin_amdgcn_s_setprio(1);
            a0 = MFMA(Wx[0], xf, a0);
            a1 = MFMA(Wx[1], xf, a1);
            a2 = MFMA(Wx[2], xf, a2);
            a3 = MFMA(Wx[3], xf, a3);
            __builtin_amdgcn_s_setprio(0);
        };

        // FIN phase: folded activations + cell update + pack + LDS write.
        auto finP = [&](int m, const f32x4& a0, const f32x4& a1,
                        const f32x4& a2, const f32x4& a3) {
            float hvv[4];
#pragma unroll
            for (int r = 0; r < 4; ++r) {
                float A = __builtin_amdgcn_exp2f(a0[r]);
                float F = __builtin_amdgcn_exp2f(a1[r]);
                float B = __builtin_amdgcn_exp2f(a2[r]);
                float D = __builtin_amdgcn_exp2f(a3[r]);
                float P = (1.0f + A) * (1.0f + B);
                float Fp = 1.0f + F;
                float R = __builtin_amdgcn_rcpf(P * Fp);
                float cn = (c[m][r] * P + (B - 1.0f) * Fp) * R;
                c[m][r] = cn;
                float C = __builtin_amdgcn_exp2f(PG * cn);
                float R2 = __builtin_amdgcn_rcpf((1.0f + D) * (C + 1.0f));
                hvv[r] = (C - 1.0f) * R2;
            }
            *(u32x2*)(wbp + wo + m * 4096) =
                (u32x2){pk2(hvv[0], hvv[1]), pk2(hvv[2], hvv[3])};
        };

        // two-stage pipeline: mfma(m+1) issues before fin(m) runs
        mfmaP(0, A0, A1, A2, A3);
        mfmaP(1, B0, B1, B2, B3);
        finP(0, A0, A1, A2, A3);
        mfmaP(2, A0, A1, A2, A3);
        finP(1, B0, B1, B2, B3);
        mfmaP(3, B0, B1, B2, B3);
        finP(2, A0, A1, A2, A3);
        mfmaP(4, A0, A1, A2, A3);
        finP(3, B0, B1, B2, B3);
        mfmaP(5, B0, B1, B2, B3);
        finP(4, A0, A1, A2, A3);
        mfmaP(6, A0, A1, A2, A3);
        finP(5, B0, B1, B2, B3);
        mfmaP(7, B0, B1, B2, B3);
        finP(6, A0, A1, A2, A3);
        mfmaP(8, A0, A1, A2, A3);
        finP(7, B0, B1, B2, B3);
        mfmaP(9, B0, B1, B2, B3);
        finP(8, A0, A1, A2, A3);
        finP(9, B0, B1, B2, B3);

        __syncthreads();   // h_new + pos visible; old-buffer reads all done pre-barrier
    }

    // --- epilogue: preds[T-1] = pos_T from h_T (buffer 0, Tn even)
#pragma unroll
    for (int m = 0; m < MT; ++m) {
        if ((m & 7) != wv) continue;
        const char* rbp = hT[0];
        const int mo = m * 4096;
        bf16x8 H0 = *(const bf16x8*)(rbp + ro0 + mo);
        bf16x8 H1 = *(const bf16x8*)(rbp + ro1 + mo);
        bf16x8 H2 = *(const bf16x8*)(rbp + ro2 + mo);
        bf16x8 H3 = *(const bf16x8*)(rbp + ro3 + mo);
        f32x4 pacc = {0.f, 0.f, 0.f, 0.f};
        pacc = MFMA(php[0], H0, pacc);
        pacc = MFMA(php[1], H1, pacc);
        pacc = MFMA(php[2], H2, pacc);
        pacc = MFMA(php[3], H3, pacc);
        if (lg == 0) {
            float2 pp = posb[Tn & 1][m * 16 + li];
            float fx = pp.x + pacc[0] + phb0;
            float fy = pp.y + pacc[1] + phb1;
            size_t o = ((size_t)(r0 + m * 16 + li) * Tn + (Tn - 1)) * 2;
            *(float2*)(preds + o) = make_float2(fx, fy);
        }
    }
#undef MT
#undef ROWS
#undef BUFB
}

extern "C" void kernel_launch(void* const* d_in, const int* in_sizes, int n_in,
                              void* d_out, int out_size, void* d_ws, size_t ws_size,
                              hipStream_t stream)
{
    (void)in_sizes; (void)n_in; (void)out_size; (void)d_ws; (void)ws_size;
    const float* eh   = (const float*)d_in[0];
    const float* ec   = (const float*)d_in[1];
    const float* lp   = (const float*)d_in[2];
    const float* gpw1 = (const float*)d_in[3];
    const float* gpb1 = (const float*)d_in[4];
    const float* gpw2 = (const float*)d_in[5];
    const float* gpb2 = (const float*)d_in[6];
    const float* prw1 = (const float*)d_in[7];
    const float* prb1 = (const float*)d_in[8];
    const float* prw2 = (const float*)d_in[9];
    const float* prb2 = (const float*)d_in[10];
    const float* wih  = (const float*)d_in[11];
    const float* whh  = (const float*)d_in[12];
    const float* bih  = (const float*)d_in[13];
    const float* bhh  = (const float*)d_in[14];
    const float* phw  = (const float*)d_in[15];
    const float* phb  = (const float*)d_in[16];

    float* out = (float*)d_out;
    float* preds = out;                                            // [B,G,T,2]
    float* goals = out + (size_t)Bn * Gn * Tn * 2;                 // [B,G,2]
    float* probs = out + (size_t)Bn * Gn * Tn * 2 + (size_t)Bn * Gn * 2;  // [B,G]

    k_phaseA<<<Bn / 64, 256, 0, stream>>>(eh, lp, gpw1, gpb1, gpw2, gpb2,
                                          prw1, prb1, prw2, prb2, goals, probs);
    k_lstm<<<(Bn * Gn) / 160, 512, 0, stream>>>(eh, ec, lp, wih, whh, bih, bhh,
                                                phw, phb, goals, preds);
}